// Round 8
// baseline (258.567 us; speedup 1.0000x reference)
//
#include <hip/hip_runtime.h>
#include <hip/hip_bf16.h>
#include <stdint.h>

#define S 9216
#define C 256
#define NB 8
#define EPS 1e-5f

typedef __attribute__((ext_vector_type(8))) short bf16x8;
typedef __attribute__((ext_vector_type(4))) float f32x4;
typedef unsigned short u16;
typedef unsigned int u32;

// ---------------- ws layout (bytes) ----------------
#define WS_SC   0          // sc_sh fp32 [512]
#define WS_RX   4096       // rx fp32 [8][256]
#define WS_DS   16384      // diagS fp32 [256]
#define WS_U    20480      // uvec fp32 [8][256]
#define WS_PV2  32768      // pvec fp32 [8][256]
#define WS_P1   45056      // p1 fp32 [256]
#define WS_PW   49152      // pw fp32 [256]
#define WS_SHW  53248      // shw fp32 [256]
#define WS_CZ   57344      // constz fp32 [8][256]
#define WS_WKT  65536      // wkT bf16 [256][256]
#define WS_WPT  196608     // wpT bf16 [256][256]
#define WS_WPV  327680     // Wpv bf16 [256][256]
#define WS_GB   458752     // Gb bf16 [8][256][256]
#define WS_T1   1507328    // T1 bf16 [8][256][256]
#define WS_AC2  2555904    // Ac2 bf16 [8][256][256]
#define WS_M    3604480    // M' bf16 [8][256][256]
#define WS_XB   5242880    // xb bf16 [8][256][9216]   (c-major raw)
#define WS_XBT  42991616   // xbT bf16 [8][9216][256]  (s-major raw)
#define WS_P    80740352   // partials fp32 [8][3][16][128][128] = 25.2MB

__device__ __forceinline__ float bf2f(u16 b) { return __uint_as_float((u32)b << 16); }
__device__ __forceinline__ u16 cvt1(float x) {
    __hip_bfloat16 h = __float2bfloat16(x);
    return *(u16*)&h;
}
__device__ __forceinline__ bf16x8 pack8(float4 a, float4 b) {
    union { bf16x8 v; u16 h[8]; } u;
    u.h[0] = cvt1(a.x); u.h[1] = cvt1(a.y); u.h[2] = cvt1(a.z); u.h[3] = cvt1(a.w);
    u.h[4] = cvt1(b.x); u.h[5] = cvt1(b.y); u.h[6] = cvt1(b.z); u.h[7] = cvt1(b.w);
    return u.v;
}

// ---------------- weight transposes ----------------
__global__ __launch_bounds__(256)
void wt_build(const float* __restrict__ w_qkv, const float* __restrict__ w_proj,
              u16* __restrict__ wkT, u16* __restrict__ wpT) {
    const int r0 = blockIdx.x, c = threadIdx.x;
    if (r0 < 256) {
        wkT[(size_t)r0 * 256 + c] = cvt1(w_qkv[(size_t)c * 768 + 256 + r0]);
    } else {
        const int o = r0 - 256;
        wpT[(size_t)o * 256 + c] = cvt1(w_proj[(size_t)c * 256 + o]);
    }
}

// ---------------- Wpv[o][c] = sum_e wpT[o][e] * w_qkv[c][512+e] ----------------
__global__ __launch_bounds__(256)
void wpv_gemm(const u16* __restrict__ wpT, const float* __restrict__ w_qkv,
              u16* __restrict__ Wpv) {
    const int bid = blockIdx.x;
    const int ot = bid >> 2, ct = bid & 3;
    const int tid = threadIdx.x;
    const int w = tid >> 6, l = tid & 63, g = l >> 4, r = l & 15;
    const int wr = w >> 1, wc = w & 1;
    const int mb = ot * 64 + wr * 32, nb = ct * 64 + wc * 32;

    f32x4 acc[2][2];
    #pragma unroll
    for (int i = 0; i < 2; ++i)
        #pragma unroll
        for (int j = 0; j < 2; ++j) acc[i][j] = (f32x4){0.f, 0.f, 0.f, 0.f};

    for (int k0 = 0; k0 < 256; k0 += 32) {
        bf16x8 a[2], b[2];
        #pragma unroll
        for (int i = 0; i < 2; ++i)
            a[i] = *(const bf16x8*)&wpT[(size_t)(mb + i * 16 + r) * 256 + k0 + g * 8];
        #pragma unroll
        for (int j = 0; j < 2; ++j) {
            const float* p = w_qkv + (size_t)(nb + j * 16 + r) * 768 + 512 + k0 + g * 8;
            b[j] = pack8(*(const float4*)p, *(const float4*)(p + 4));
        }
        #pragma unroll
        for (int i = 0; i < 2; ++i)
            #pragma unroll
            for (int j = 0; j < 2; ++j)
                acc[i][j] = __builtin_amdgcn_mfma_f32_16x16x32_bf16(a[i], b[j], acc[i][j], 0, 0, 0);
    }
    #pragma unroll
    for (int i = 0; i < 2; ++i)
        #pragma unroll
        for (int q = 0; q < 4; ++q) {
            const int row = mb + i * 16 + g * 4 + q;
            #pragma unroll
            for (int j = 0; j < 2; ++j)
                Wpv[(size_t)row * 256 + nb + j * 16 + r] = cvt1(acc[i][j][q]);
        }
}

// ---------------- cvt: inp fp32 -> xb (c-major bf16) + xbT (s-major bf16) + rx/diagS ----------------
__global__ __launch_bounds__(256)
void cvt(const float* __restrict__ inp, u16* __restrict__ xb, u16* __restrict__ xbT,
         float* __restrict__ rx, float* __restrict__ diagS) {
    __shared__ u16 T[64 * 258];   // T[s_local][c], stride 258 u16 (conflict-free)
    const int bid = blockIdx.x;   // 1152 = 8z * 144sb
    const int z = bid / 144, sb = bid % 144;
    const int s0 = sb * 64;
    const int t = threadIdx.x;
    const int lane = t & 63, w = t >> 6;

    for (int it = 0; it < 64; ++it) {
        const int row = it * 4 + w;
        const size_t gidx = ((size_t)(z * C + row)) * S + s0 + lane;
        float v = inp[gidx];
        u16 b = cvt1(v);
        xb[gidx] = b;
        T[lane * 258 + row] = b;
    }
    __syncthreads();
    {   // column sums: c = t
        float sum = 0.f, ssq = 0.f;
        #pragma unroll 8
        for (int sl = 0; sl < 64; ++sl) {
            float v = bf2f(T[sl * 258 + t]);
            sum += v; ssq = fmaf(v, v, ssq);
        }
        atomicAdd(&rx[z * 256 + t], sum);
        atomicAdd(&diagS[t], ssq);
    }
    // write xbT rows (512B contiguous runs)
    const int sl = t >> 2, q4 = t & 3;
    u16* dst = xbT + ((size_t)z * S + s0 + sl) * 256 + q4 * 64;
    const u16* src = &T[sl * 258 + q4 * 64];
    #pragma unroll
    for (int k = 0; k < 8; ++k) {
        u32 a0 = *(const u32*)&src[k * 8 + 0];
        u32 a1 = *(const u32*)&src[k * 8 + 2];
        u32 a2 = *(const u32*)&src[k * 8 + 4];
        u32 a3 = *(const u32*)&src[k * 8 + 6];
        uint4 q; q.x = a0; q.y = a1; q.z = a2; q.w = a3;
        *(uint4*)&dst[k * 8] = q;
    }
}

// ---------------- bn_fin: sc_sh from diagS + rx ----------------
__global__ __launch_bounds__(256)
void bn_fin(const float* __restrict__ diagS, const float* __restrict__ rx,
            const float* __restrict__ gamma, const float* __restrict__ beta,
            float* __restrict__ sc_sh) {
    const int c = threadIdx.x;
    float s = 0.f;
    #pragma unroll
    for (int z = 0; z < NB; ++z) s += rx[z * 256 + c];
    const float q = diagS[c];
    const float invN = 1.0f / (float)(NB * S);
    float m = s * invN;
    float var = q * invN - m * m;
    float rstd = rsqrtf(var + EPS);
    float sc = gamma[c] * rstd;
    sc_sh[c] = sc;
    sc_sh[C + c] = beta[c] - m * sc;
}

// ---------------- gram: P[z][tile][sp] = 128x128 partial of xb.xb^T; direct-frag, no LDS ----------------
__global__ __launch_bounds__(256)
void gram(const u16* __restrict__ xb, float* __restrict__ P) {
    const int bid = blockIdx.x;                  // 384 = 8*48
    const int wid = (bid & 7) * 48 + (bid >> 3); // z = xcd
    const int z = wid / 48;
    const int rem = wid % 48;
    const int tile = rem >> 4;                   // 0:(0,0) 1:(1,1) 2:(0,1)
    const int sp = rem & 15;
    const int ti = (tile == 1) ? 1 : 0;
    const int tj = (tile == 0) ? 0 : 1;

    const int t = threadIdx.x;
    const int w = t >> 6, l = t & 63, g = l >> 4, r = l & 15;
    const int wr = w >> 1, wc = w & 1;

    const u16* Az = xb + (size_t)z * C * S;
    const u16* Ab = Az + (size_t)(ti * 128 + wr * 64) * S;
    const u16* Bb = Az + (size_t)(tj * 128 + wc * 64) * S;

    f32x4 acc[4][4];
    #pragma unroll
    for (int i = 0; i < 4; ++i)
        #pragma unroll
        for (int j = 0; j < 4; ++j) acc[i][j] = (f32x4){0.f, 0.f, 0.f, 0.f};

    const int sbeg = sp * 576;
    for (int k0 = 0; k0 < 576; k0 += 32) {
        const int scol = sbeg + k0 + g * 8;
        bf16x8 a[4], b[4];
        #pragma unroll
        for (int i = 0; i < 4; ++i)
            a[i] = *(const bf16x8*)&Ab[(size_t)(i * 16 + r) * S + scol];
        #pragma unroll
        for (int j = 0; j < 4; ++j)
            b[j] = *(const bf16x8*)&Bb[(size_t)(j * 16 + r) * S + scol];
        #pragma unroll
        for (int i = 0; i < 4; ++i)
            #pragma unroll
            for (int j = 0; j < 4; ++j)
                acc[i][j] = __builtin_amdgcn_mfma_f32_16x16x32_bf16(a[i], b[j], acc[i][j], 0, 0, 0);
    }
    float* PP = P + (((size_t)(z * 3 + tile) * 16 + sp) << 14);
    #pragma unroll
    for (int i = 0; i < 4; ++i)
        #pragma unroll
        for (int q = 0; q < 4; ++q) {
            const int row = wr * 64 + i * 16 + g * 4 + q;
            #pragma unroll
            for (int j = 0; j < 4; ++j)
                PP[row * 128 + wc * 64 + j * 16 + r] = acc[i][j][q];
        }
}

// ---------------- prep_g2: Gb = affine(sum_sp P) with symmetric mirror ----------------
__global__ __launch_bounds__(256)
void prep_g2(const float* __restrict__ P, const float* __restrict__ rx,
             const float* __restrict__ sc_sh, u16* __restrict__ Gb) {
    __shared__ float scs[256], shs[256], rxl[256];
    const int bid = blockIdx.x;   // 24
    const int z = bid / 3, tile = bid % 3;
    const int ti = (tile == 1) ? 1 : 0;
    const int tj = (tile == 0) ? 0 : 1;
    const int t = threadIdx.x;
    scs[t] = sc_sh[t]; shs[t] = sc_sh[C + t]; rxl[t] = rx[z * 256 + t];
    __syncthreads();
    const int rr = t >> 1, cc0 = (t & 1) * 64;
    float s[64];
    #pragma unroll
    for (int e = 0; e < 64; ++e) s[e] = 0.f;
    for (int sp = 0; sp < 16; ++sp) {
        const float* src = P + (((size_t)(z * 3 + tile) * 16 + sp) << 14) + rr * 128 + cc0;
        #pragma unroll
        for (int e4 = 0; e4 < 16; ++e4) {
            float4 v = *(const float4*)&src[e4 * 4];
            s[e4 * 4 + 0] += v.x; s[e4 * 4 + 1] += v.y;
            s[e4 * 4 + 2] += v.z; s[e4 * 4 + 3] += v.w;
        }
    }
    const int gr = ti * 128 + rr;
    const float scr = scs[gr], shr = shs[gr], rxr = rxl[gr];
    u16 o[64];
    #pragma unroll
    for (int e = 0; e < 64; ++e) {
        const int gc = tj * 128 + cc0 + e;
        float v = scr * scs[gc] * s[e] + scr * shs[gc] * rxr
                + shr * scs[gc] * rxl[gc] + 9216.f * shr * shs[gc];
        o[e] = cvt1(v);
    }
    u16* Gz = Gb + (size_t)z * 65536;
    u16* dst = Gz + (size_t)gr * 256 + tj * 128 + cc0;
    #pragma unroll
    for (int k = 0; k < 8; ++k) *(uint4*)&dst[k * 8] = *(uint4*)&o[k * 8];
    if (ti != tj) {   // mirror (value is symmetric under the affine)
        #pragma unroll
        for (int e = 0; e < 64; ++e) {
            const int gc = tj * 128 + cc0 + e;
            Gz[(size_t)gc * 256 + ti * 128 + rr] = o[e];
        }
    }
}

// ---------------- prep_v: uvec/pvec per z; z0: p1, pw, shw ----------------
__global__ __launch_bounds__(256)
void prep_v(const float* __restrict__ sc_sh, const float* __restrict__ rx,
            const u16* __restrict__ wkT, const u16* __restrict__ Wpv,
            const u16* __restrict__ wpT, const float* __restrict__ w_qkv,
            const float* __restrict__ b_qkv,
            float* __restrict__ uvec, float* __restrict__ pvec,
            float* __restrict__ p1, float* __restrict__ pw, float* __restrict__ shw) {
    const int z = blockIdx.x, t = threadIdx.x;
    __shared__ float rsn[256], bvl[256], shl[256];
    rsn[t] = sc_sh[t] * rx[z * 256 + t] + 9216.f * sc_sh[C + t];
    bvl[t] = b_qkv[512 + t];
    shl[t] = sc_sh[C + t];
    __syncthreads();
    float au = 0.f, ap = 0.f, apw = 0.f;
    const u16* krow = wkT + (size_t)t * 256;
    const u16* prow = Wpv + (size_t)t * 256;
    for (int cb = 0; cb < 256; cb += 8) {
        uint4 kp = *(const uint4*)&krow[cb];
        uint4 pp = *(const uint4*)&prow[cb];
        const u16* kk = (const u16*)&kp;
        const u16* qq = (const u16*)&pp;
        #pragma unroll
        for (int u = 0; u < 8; ++u) {
            au = fmaf(bf2f(kk[u]), rsn[cb + u], au);
            float pv = bf2f(qq[u]);
            ap = fmaf(pv, rsn[cb + u], ap);
            apw = fmaf(pv, shl[cb + u], apw);
        }
    }
    uvec[z * 256 + t] = au;
    pvec[z * 256 + t] = ap;
    if (z == 0) {
        float a1 = 0.f, asw = 0.f;
        const u16* wrow = wpT + (size_t)t * 256;
        for (int cb = 0; cb < 256; cb += 8) {
            uint4 wp = *(const uint4*)&wrow[cb];
            const u16* ww = (const u16*)&wp;
            #pragma unroll
            for (int u = 0; u < 8; ++u) a1 = fmaf(bf2f(ww[u]), bvl[cb + u], a1);
        }
        for (int c = 0; c < 256; ++c)
            asw = fmaf(w_qkv[(size_t)c * 768 + t], shl[c], asw);
        p1[t] = a1;
        pw[t] = apw;
        shw[t] = asw;
    } else if (t == 0) {
        // nothing
    }
    if (z == 0) { /* pw written above */ } else if (z == 1 && t < 0) { }
}

// ---------------- t1: T1[z][o][c] = sum_c' Wpv[o][c'] * Gb[z][c][c'] ----------------
__global__ __launch_bounds__(256)
void t1_gemm(const u16* __restrict__ Wpv, const u16* __restrict__ Gb,
             u16* __restrict__ T1) {
    const int bid = blockIdx.x;
    const int wid = (bid & 7) * 16 + (bid >> 3);
    const int z = wid >> 4, ot = (wid >> 2) & 3, ct = wid & 3;
    const int tid = threadIdx.x;
    const int w = tid >> 6, l = tid & 63, g = l >> 4, r = l & 15;
    const int wr = w >> 1, wc = w & 1;
    const int mb = ot * 64 + wr * 32, nb = ct * 64 + wc * 32;
    const u16* Gz = Gb + (size_t)z * 65536;

    f32x4 acc[2][2];
    #pragma unroll
    for (int i = 0; i < 2; ++i)
        #pragma unroll
        for (int j = 0; j < 2; ++j) acc[i][j] = (f32x4){0.f, 0.f, 0.f, 0.f};

    for (int k0 = 0; k0 < 256; k0 += 32) {
        bf16x8 a[2], b[2];
        #pragma unroll
        for (int i = 0; i < 2; ++i)
            a[i] = *(const bf16x8*)&Wpv[(size_t)(mb + i * 16 + r) * 256 + k0 + g * 8];
        #pragma unroll
        for (int j = 0; j < 2; ++j)
            b[j] = *(const bf16x8*)&Gz[(size_t)(nb + j * 16 + r) * 256 + k0 + g * 8];
        #pragma unroll
        for (int i = 0; i < 2; ++i)
            #pragma unroll
            for (int j = 0; j < 2; ++j)
                acc[i][j] = __builtin_amdgcn_mfma_f32_16x16x32_bf16(a[i], b[j], acc[i][j], 0, 0, 0);
    }
    u16* Tz = T1 + (size_t)z * 65536;
    #pragma unroll
    for (int i = 0; i < 2; ++i)
        #pragma unroll
        for (int q = 0; q < 4; ++q) {
            const int row = mb + i * 16 + g * 4 + q;
            #pragma unroll
            for (int j = 0; j < 2; ++j)
                Tz[(size_t)row * 256 + nb + j * 16 + r] = cvt1(acc[i][j][q]);
        }
}

// ---------------- ac2: Ac2[z][o][d] = sum_c T1[o][c]*wkT[d][c] + rank-1 terms ----------------
__global__ __launch_bounds__(256)
void ac2_gemm(const u16* __restrict__ T1, const u16* __restrict__ wkT,
              const float* __restrict__ uvec, const float* __restrict__ pvec,
              const float* __restrict__ p1, const float* __restrict__ b_qkv,
              u16* __restrict__ Ac2) {
    const int bid = blockIdx.x;
    const int wid = (bid & 7) * 16 + (bid >> 3);
    const int z = wid >> 4, ot = (wid >> 2) & 3, ct = wid & 3;
    const int tid = threadIdx.x;
    const int w = tid >> 6, l = tid & 63, g = l >> 4, r = l & 15;
    const int wr = w >> 1, wc = w & 1;
    const int mb = ot * 64 + wr * 32, nb = ct * 64 + wc * 32;
    const u16* Tz = T1 + (size_t)z * 65536;

    f32x4 acc[2][2];
    #pragma unroll
    for (int i = 0; i < 2; ++i)
        #pragma unroll
        for (int j = 0; j < 2; ++j) acc[i][j] = (f32x4){0.f, 0.f, 0.f, 0.f};

    for (int k0 = 0; k0 < 256; k0 += 32) {
        bf16x8 a[2], b[2];
        #pragma unroll
        for (int i = 0; i < 2; ++i)
            a[i] = *(const bf16x8*)&Tz[(size_t)(mb + i * 16 + r) * 256 + k0 + g * 8];
        #pragma unroll
        for (int j = 0; j < 2; ++j)
            b[j] = *(const bf16x8*)&wkT[(size_t)(nb + j * 16 + r) * 256 + k0 + g * 8];
        #pragma unroll
        for (int i = 0; i < 2; ++i)
            #pragma unroll
            for (int j = 0; j < 2; ++j)
                acc[i][j] = __builtin_amdgcn_mfma_f32_16x16x32_bf16(a[i], b[j], acc[i][j], 0, 0, 0);
    }
    u16* Az = Ac2 + (size_t)z * 65536;
    #pragma unroll
    for (int i = 0; i < 2; ++i)
        #pragma unroll
        for (int q = 0; q < 4; ++q) {
            const int row = mb + i * 16 + g * 4 + q;
            const float p1r = p1[row];
            const float pvr = pvec[z * 256 + row];
            #pragma unroll
            for (int j = 0; j < 2; ++j) {
                const int col = nb + j * 16 + r;
                const float bkv = b_qkv[256 + col];
                const float uv = uvec[z * 256 + col];
                float v = acc[i][j][q] + p1r * (uv + 9216.f * bkv) + pvr * bkv;
                Az[(size_t)row * 256 + col] = cvt1(v);
            }
        }
}

// ---------------- m: M'[z][o][c] = (Wpv[o][c] + sum_d Ac2[o][d]*wq[c][d]) * sc[c]; cz' ----------------
__global__ __launch_bounds__(256)
void m_gemm(const u16* __restrict__ Ac2, const float* __restrict__ w_qkv,
            const u16* __restrict__ Wpv, const float* __restrict__ p1,
            const float* __restrict__ pw, const float* __restrict__ shw,
            const float* __restrict__ b_qkv, const float* __restrict__ b_proj,
            const float* __restrict__ sc_sh,
            u16* __restrict__ M, float* __restrict__ constz) {
    const int bid = blockIdx.x;
    const int wid = (bid & 7) * 16 + (bid >> 3);
    const int z = wid >> 4, ot = (wid >> 2) & 3, ct = wid & 3;
    const int tid = threadIdx.x;
    const int w = tid >> 6, l = tid & 63, g = l >> 4, r = l & 15;
    const int wr = w >> 1, wc = w & 1;
    const int mb = ot * 64 + wr * 32, nb = ct * 64 + wc * 32;
    const u16* Az = Ac2 + (size_t)z * 65536;
    const bool docz = (wc == 0 && ct == 0);

    f32x4 acc[2][2];
    #pragma unroll
    for (int i = 0; i < 2; ++i)
        #pragma unroll
        for (int j = 0; j < 2; ++j) acc[i][j] = (f32x4){0.f, 0.f, 0.f, 0.f};
    float cacc[2] = {0.f, 0.f};

    for (int k0 = 0; k0 < 256; k0 += 32) {
        bf16x8 a[2], b[2];
        #pragma unroll
        for (int i = 0; i < 2; ++i)
            a[i] = *(const bf16x8*)&Az[(size_t)(mb + i * 16 + r) * 256 + k0 + g * 8];
        #pragma unroll
        for (int j = 0; j < 2; ++j) {
            const float* p = w_qkv + (size_t)(nb + j * 16 + r) * 768 + k0 + g * 8;
            b[j] = pack8(*(const float4*)p, *(const float4*)(p + 4));
        }
        if (docz) {
            float bqv[8];
            #pragma unroll
            for (int u = 0; u < 8; ++u) {
                const int kg = k0 + g * 8 + u;
                bqv[u] = b_qkv[kg] + shw[kg];
            }
            #pragma unroll
            for (int i = 0; i < 2; ++i) {
                bf16x8 av = a[i];
                #pragma unroll
                for (int u = 0; u < 8; ++u)
                    cacc[i] = fmaf(bf2f((u16)av[u]), bqv[u], cacc[i]);
            }
        }
        #pragma unroll
        for (int i = 0; i < 2; ++i)
            #pragma unroll
            for (int j = 0; j < 2; ++j)
                acc[i][j] = __builtin_amdgcn_mfma_f32_16x16x32_bf16(a[i], b[j], acc[i][j], 0, 0, 0);
    }
    u16* Mz = M + (size_t)z * 65536;
    #pragma unroll
    for (int i = 0; i < 2; ++i)
        #pragma unroll
        for (int q = 0; q < 4; ++q) {
            const int row = mb + i * 16 + g * 4 + q;
            #pragma unroll
            for (int j = 0; j < 2; ++j) {
                const int col = nb + j * 16 + r;
                float v = acc[i][j][q] + bf2f(Wpv[(size_t)row * 256 + col]);
                Mz[(size_t)row * 256 + col] = cvt1(v * sc_sh[col]);
            }
        }
    if (docz) {
        #pragma unroll
        for (int i = 0; i < 2; ++i) {
            float rr2 = cacc[i];
            rr2 += __shfl_xor(rr2, 16, 64);
            rr2 += __shfl_xor(rr2, 32, 64);
            if (l < 16) {
                const int o = mb + i * 16 + l;
                constz[z * 256 + o] = b_proj[o] + p1[o] + pw[o] + rr2;
            }
        }
    }
}

// ---------------- out: OUT[o][s] = M'[o][:] . xraw[s][:] + cz'[o] + inp[o][s]; LDS-free ----------------
__global__ __launch_bounds__(256)
void out_gemm(const u16* __restrict__ M, const u16* __restrict__ xbT,
              const float* __restrict__ inp, const float* __restrict__ constz,
              float* __restrict__ out) {
    const int bid = blockIdx.x;                   // 576 = 8*72; z = xcd
    const int wid = (bid & 7) * 72 + (bid >> 3);
    const int z = wid / 72, st = wid % 72;
    const int t = threadIdx.x;
    const int w = t >> 6, l = t & 63, g = l >> 4, r = l & 15;
    const int wo = w >> 1, wsb = w & 1;

    const u16* Mz = M + (size_t)z * 65536 + (size_t)(wo * 128) * 256;
    const u16* Bz = xbT + ((size_t)z * S + st * 128 + wsb * 64) * 256;

    f32x4 acc[8][4];
    #pragma unroll
    for (int i = 0; i < 8; ++i)
        #pragma unroll
        for (int j = 0; j < 4; ++j) acc[i][j] = (f32x4){0.f, 0.f, 0.f, 0.f};

    for (int k0 = 0; k0 < 256; k0 += 32) {
        bf16x8 a[8], b[4];
        #pragma unroll
        for (int i = 0; i < 8; ++i)
            a[i] = *(const bf16x8*)&Mz[(size_t)(i * 16 + r) * 256 + k0 + g * 8];
        #pragma unroll
        for (int j = 0; j < 4; ++j)
            b[j] = *(const bf16x8*)&Bz[(size_t)(j * 16 + r) * 256 + k0 + g * 8];
        #pragma unroll
        for (int i = 0; i < 8; ++i)
            #pragma unroll
            for (int j = 0; j < 4; ++j)
                acc[i][j] = __builtin_amdgcn_mfma_f32_16x16x32_bf16(a[i], b[j], acc[i][j], 0, 0, 0);
    }
    #pragma unroll
    for (int i = 0; i < 8; ++i) {
        #pragma unroll
        for (int q = 0; q < 4; ++q) {
            const int o = wo * 128 + i * 16 + g * 4 + q;
            const float cz = constz[z * 256 + o];
            const size_t base = ((size_t)(z * C + o)) * S + st * 128 + wsb * 64;
            #pragma unroll
            for (int j = 0; j < 4; ++j) {
                const int sl = j * 16 + r;
                out[base + sl] = acc[i][j][q] + cz + inp[base + sl];
            }
        }
    }
}

extern "C" void kernel_launch(void* const* d_in, const int* in_sizes, int n_in,
                              void* d_out, int out_size, void* d_ws, size_t ws_size,
                              hipStream_t stream) {
    const float* inp    = (const float*)d_in[0];
    const float* gamma  = (const float*)d_in[1];
    const float* beta   = (const float*)d_in[2];
    const float* w_qkv  = (const float*)d_in[3];
    const float* b_qkv  = (const float*)d_in[4];
    const float* w_proj = (const float*)d_in[5];
    const float* b_proj = (const float*)d_in[6];
    float* out = (float*)d_out;

    char* ws = (char*)d_ws;
    float* sc_sh = (float*)(ws + WS_SC);
    float* rx    = (float*)(ws + WS_RX);
    float* diagS = (float*)(ws + WS_DS);
    float* uvec  = (float*)(ws + WS_U);
    float* pvec  = (float*)(ws + WS_PV2);
    float* p1    = (float*)(ws + WS_P1);
    float* pw    = (float*)(ws + WS_PW);
    float* shw   = (float*)(ws + WS_SHW);
    float* cz    = (float*)(ws + WS_CZ);
    u16*   wkT   = (u16*)(ws + WS_WKT);
    u16*   wpT   = (u16*)(ws + WS_WPT);
    u16*   Wpv   = (u16*)(ws + WS_WPV);
    u16*   Gb    = (u16*)(ws + WS_GB);
    u16*   T1    = (u16*)(ws + WS_T1);
    u16*   Ac2   = (u16*)(ws + WS_AC2);
    u16*   Mm    = (u16*)(ws + WS_M);
    u16*   xb    = (u16*)(ws + WS_XB);
    u16*   xbT   = (u16*)(ws + WS_XBT);
    float* P     = (float*)(ws + WS_P);

    hipMemsetAsync(rx, 0, NB * 256 * sizeof(float), stream);
    hipMemsetAsync(diagS, 0, 256 * sizeof(float), stream);

    wt_build<<<dim3(512), dim3(256), 0, stream>>>(w_qkv, w_proj, wkT, wpT);
    wpv_gemm<<<dim3(16), dim3(256), 0, stream>>>(wpT, w_qkv, Wpv);
    cvt<<<dim3(1152), dim3(256), 0, stream>>>(inp, xb, xbT, rx, diagS);
    bn_fin<<<dim3(1), dim3(256), 0, stream>>>(diagS, rx, gamma, beta, sc_sh);
    gram<<<dim3(384), dim3(256), 0, stream>>>(xb, P);
    prep_g2<<<dim3(24), dim3(256), 0, stream>>>(P, rx, sc_sh, Gb);
    prep_v<<<dim3(NB), dim3(256), 0, stream>>>(sc_sh, rx, wkT, Wpv, wpT, w_qkv, b_qkv,
                                               uvec, pvec, p1, pw, shw);
    t1_gemm<<<dim3(128), dim3(256), 0, stream>>>(Wpv, Gb, T1);
    ac2_gemm<<<dim3(128), dim3(256), 0, stream>>>(T1, wkT, uvec, pvec, p1, b_qkv, Ac2);
    m_gemm<<<dim3(128), dim3(256), 0, stream>>>(Ac2, w_qkv, Wpv, p1, pw, shw,
                                                b_qkv, b_proj, sc_sh, Mm, cz);
    out_gemm<<<dim3(576), dim3(256), 0, stream>>>(Mm, xbT, inp, cz, out);
}